// Round 2
// baseline (1252.620 us; speedup 1.0000x reference)
//
#include <hip/hip_runtime.h>
#include <hip/hip_bf16.h>
#include <math.h>

#define N_SEQ 1024
#define CS 384
#define CZ 128
#define NH 16
#define CH 24

typedef float  floatx4 __attribute__((ext_vector_type(4)));
typedef short  shortx8 __attribute__((ext_vector_type(8)));
typedef unsigned int uintx4 __attribute__((ext_vector_type(4)));
typedef unsigned int uintx2 __attribute__((ext_vector_type(2)));

__device__ __forceinline__ unsigned short f2bf(float f){
  union { float fv; unsigned u; } c; c.fv = f;
  unsigned u = c.u;
  return (unsigned short)((u + 0x7fffu + ((u >> 16) & 1u)) >> 16);
}
__device__ __forceinline__ float bf2f(unsigned short s){
  union { unsigned u; float fv; } c; c.u = ((unsigned)s) << 16; return c.fv;
}
__device__ __forceinline__ float bf_lo(unsigned u){
  union { unsigned uu; float f; } c; c.uu = u << 16; return c.f;
}
__device__ __forceinline__ float bf_hi(unsigned u){
  union { unsigned uu; float f; } c; c.uu = u & 0xffff0000u; return c.f;
}
__device__ __forceinline__ float sigmoidf_(float x){ return 1.f / (1.f + __expf(-x)); }

// ---------------- K0: precompute bias weights ----------------
// wprodT[h][c] = bf16(lnb_w[c]*wb[c][h]); sums[h]=sum_c lnb_w[c]*wb[c][h]; sums[16+h]=sum_c lnb_b[c]*wb[c][h]
__global__ __launch_bounds__(256) void prep_kernel(
    const float* __restrict__ lnb_w, const float* __restrict__ lnb_b,
    const float* __restrict__ wb,
    unsigned short* __restrict__ wprodT, float* __restrict__ sums)
{
  int t = threadIdx.x;
  int h = t >> 4;
  int g = t & 15;
  float pw = 0.f, pb = 0.f;
  unsigned short loc[8];
  #pragma unroll
  for (int e = 0; e < 8; ++e){
    int c = g*8 + e;
    float lw = lnb_w[c], lb = lnb_b[c], w = wb[c*NH + h];
    float p = lw * w;
    loc[e] = f2bf(p);
    pw += p; pb += lb * w;
  }
  #pragma unroll
  for (int e = 0; e < 8; ++e) wprodT[h*CZ + g*8 + e] = loc[e];
  #pragma unroll
  for (int off = 1; off < 16; off <<= 1){
    pw += __shfl_xor(pw, off);
    pb += __shfl_xor(pb, off);
  }
  if (g == 0){ sums[h] = pw; sums[16+h] = pb; }
}

// ---------------- K1: fused LN(a), LN(s)*lns_w + AdaLN GEMM ----------------
// out = sigmoid(xs@ws + bs) * xa + xs@wns
__global__ __launch_bounds__(384) void adaln_kernel(
    const float* __restrict__ a_i, const float* __restrict__ s_i,
    const float* __restrict__ lns_w,
    const float* __restrict__ W1, const float* __restrict__ B1,
    const float* __restrict__ W2, float* __restrict__ OUT)
{
  int r0 = blockIdx.x * 4;
  int t  = threadIdx.x;
  __shared__ float xs[4][CS];
  __shared__ float xa[4][CS];
  __shared__ float red[6][16];
  float av[4], sv[4], pa[4], qa[4], ps[4], qs[4];
  #pragma unroll
  for (int rr = 0; rr < 4; ++rr){
    float a = a_i[(size_t)(r0+rr)*CS + t];
    float s = s_i[(size_t)(r0+rr)*CS + t];
    av[rr] = a; sv[rr] = s;
    pa[rr] = a; qa[rr] = a*a; ps[rr] = s; qs[rr] = s*s;
  }
  #pragma unroll
  for (int off = 1; off < 64; off <<= 1){
    #pragma unroll
    for (int rr = 0; rr < 4; ++rr){
      pa[rr] += __shfl_xor(pa[rr], off);
      qa[rr] += __shfl_xor(qa[rr], off);
      ps[rr] += __shfl_xor(ps[rr], off);
      qs[rr] += __shfl_xor(qs[rr], off);
    }
  }
  int w = t >> 6;
  if ((t & 63) == 0){
    #pragma unroll
    for (int rr = 0; rr < 4; ++rr){
      red[w][rr] = pa[rr]; red[w][4+rr] = qa[rr];
      red[w][8+rr] = ps[rr]; red[w][12+rr] = qs[rr];
    }
  }
  __syncthreads();
  float lw = lns_w[t];
  const float inv = 1.f / CS;
  #pragma unroll
  for (int rr = 0; rr < 4; ++rr){
    float Sa=0.f, Qa=0.f, Ss=0.f, Qs=0.f;
    #pragma unroll
    for (int w2 = 0; w2 < 6; ++w2){
      Sa += red[w2][rr]; Qa += red[w2][4+rr];
      Ss += red[w2][8+rr]; Qs += red[w2][12+rr];
    }
    float ma = Sa*inv, va = Qa*inv - ma*ma, ra = rsqrtf(va + 1e-5f);
    float ms = Ss*inv, vs = Qs*inv - ms*ms, rs = rsqrtf(vs + 1e-5f);
    xa[rr][t] = (av[rr] - ma) * ra;
    xs[rr][t] = (sv[rr] - ms) * rs * lw;
  }
  __syncthreads();
  int ct = t % 96, rg = t / 96, c0 = ct * 4;
  float acc1[4] = {0.f,0.f,0.f,0.f};
  float acc2[4] = {0.f,0.f,0.f,0.f};
  #pragma unroll 2
  for (int k = 0; k < CS; k += 4){
    floatx4 s4 = *(const floatx4*)&xs[rg][k];
    floatx4 w1[4], w2[4];
    #pragma unroll
    for (int j = 0; j < 4; ++j){
      size_t o = (size_t)(k+j)*CS + c0;
      w1[j] = *(const floatx4*)&W1[o];
      w2[j] = *(const floatx4*)&W2[o];
    }
    #pragma unroll
    for (int j = 0; j < 4; ++j)
      #pragma unroll
      for (int cc = 0; cc < 4; ++cc){
        acc1[cc] += s4[j] * w1[j][cc];
        acc2[cc] += s4[j] * w2[j][cc];
      }
  }
  int r = r0 + rg;
  size_t ob = (size_t)r * CS + c0;
  #pragma unroll
  for (int cc = 0; cc < 4; ++cc)
    OUT[ob+cc] = sigmoidf_(acc1[cc] + B1[c0+cc]) * xa[rg][c0+cc] + acc2[cc];
}

// ---------------- K2: fused q/k/v/g projections ----------------
__global__ __launch_bounds__(384) void qkvg_kernel(
    const float* __restrict__ A, const float* __restrict__ wq,
    const float* __restrict__ bq, const float* __restrict__ wk,
    const float* __restrict__ wv, const float* __restrict__ wg,
    float* __restrict__ qv, float* __restrict__ kv,
    float* __restrict__ vv, float* __restrict__ gv)
{
  int r0 = blockIdx.x * 4;
  int t  = threadIdx.x;
  __shared__ float xl[4][CS];
  #pragma unroll
  for (int rr = 0; rr < 4; ++rr)
    xl[rr][t] = A[(size_t)(r0+rr)*CS + t];
  __syncthreads();
  int ct = t % 96, rg = t / 96, c0 = ct * 4;
  float aq[4]={0.f,0.f,0.f,0.f}, ak[4]={0.f,0.f,0.f,0.f};
  float av4[4]={0.f,0.f,0.f,0.f}, ag[4]={0.f,0.f,0.f,0.f};
  #pragma unroll 2
  for (int k = 0; k < CS; k += 4){
    floatx4 x4 = *(const floatx4*)&xl[rg][k];
    floatx4 q[4], kk4[4], v4[4], g4[4];
    #pragma unroll
    for (int j = 0; j < 4; ++j){
      size_t o = (size_t)(k+j)*CS + c0;
      q[j]   = *(const floatx4*)&wq[o];
      kk4[j] = *(const floatx4*)&wk[o];
      v4[j]  = *(const floatx4*)&wv[o];
      g4[j]  = *(const floatx4*)&wg[o];
    }
    #pragma unroll
    for (int j = 0; j < 4; ++j)
      #pragma unroll
      for (int cc = 0; cc < 4; ++cc){
        aq[cc]  += x4[j] * q[j][cc];
        ak[cc]  += x4[j] * kk4[j][cc];
        av4[cc] += x4[j] * v4[j][cc];
        ag[cc]  += x4[j] * g4[j][cc];
      }
  }
  int r = r0 + rg;
  size_t ob = (size_t)r * CS + c0;
  #pragma unroll
  for (int cc = 0; cc < 4; ++cc){
    qv[ob+cc] = aq[cc] + bq[c0+cc];
    kv[ob+cc] = ak[cc];
    vv[ob+cc] = av4[cc];
    gv[ob+cc] = sigmoidf_(ag[cc]);
  }
}

// ---------------- K5: final — out = sigmoid(s_i@ws + bs) * (att@wo) ----------------
__global__ __launch_bounds__(384) void final_kernel(
    const float* __restrict__ att, const float* __restrict__ wo,
    const float* __restrict__ s_i, const float* __restrict__ wsm,
    const float* __restrict__ bsv, float* __restrict__ OUT)
{
  int r0 = blockIdx.x * 4;
  int t  = threadIdx.x;
  __shared__ float xo[4][CS];
  __shared__ float xsI[4][CS];
  #pragma unroll
  for (int rr = 0; rr < 4; ++rr){
    xo[rr][t]  = att[(size_t)(r0+rr)*CS + t];
    xsI[rr][t] = s_i[(size_t)(r0+rr)*CS + t];
  }
  __syncthreads();
  int ct = t % 96, rg = t / 96, c0 = ct * 4;
  float acc1[4] = {0.f,0.f,0.f,0.f};
  float acc2[4] = {0.f,0.f,0.f,0.f};
  #pragma unroll 2
  for (int k = 0; k < CS; k += 4){
    floatx4 o4 = *(const floatx4*)&xo[rg][k];
    floatx4 s4 = *(const floatx4*)&xsI[rg][k];
    floatx4 w1[4], w2[4];
    #pragma unroll
    for (int j = 0; j < 4; ++j){
      size_t o = (size_t)(k+j)*CS + c0;
      w1[j] = *(const floatx4*)&wo[o];
      w2[j] = *(const floatx4*)&wsm[o];
    }
    #pragma unroll
    for (int j = 0; j < 4; ++j)
      #pragma unroll
      for (int cc = 0; cc < 4; ++cc){
        acc1[cc] += o4[j] * w1[j][cc];
        acc2[cc] += s4[j] * w2[j][cc];
      }
  }
  int r = r0 + rg;
  size_t ob = (size_t)r * CS + c0;
  #pragma unroll
  for (int cc = 0; cc < 4; ++cc)
    OUT[ob+cc] = sigmoidf_(acc2[cc] + bsv[c0+cc]) * acc1[cc];
}

// ---------------- K3: pair bias via MFMA ----------------
__global__ __launch_bounds__(256) void bias_kernel(
    const float* __restrict__ z,
    const unsigned short* __restrict__ wprodT, const float* __restrict__ sums,
    unsigned short* __restrict__ bias)
{
  int i    = blockIdx.x >> 4;
  int j0   = (blockIdx.x & 15) * 64;
  int wave = threadIdx.x >> 6;
  int lane = threadIdx.x & 63;
  int m    = lane & 15;   // A-row (pair) for loads; head for B-frag/epilogue
  int q    = lane >> 4;
  int jbase = j0 + wave * 16;

  const unsigned short* wp = wprodT + m*CZ;
  shortx8 bfrag[4];
  #pragma unroll
  for (int s = 0; s < 4; ++s)
    bfrag[s] = *(const shortx8*)(wp + q*8 + 32*s);
  float sumw = sums[m];
  float sumb = sums[16+m];

  const float* zrow = z + ((size_t)i * N_SEQ + (size_t)(jbase + m)) * CZ;
  floatx4 acc = {0.f, 0.f, 0.f, 0.f};
  float sum = 0.f, sq = 0.f;
  #pragma unroll
  for (int s = 0; s < 4; ++s){
    floatx4 z0 = *(const floatx4*)(zrow + q*8 + 32*s);
    floatx4 z1 = *(const floatx4*)(zrow + q*8 + 32*s + 4);
    shortx8 af;
    #pragma unroll
    for (int e = 0; e < 4; ++e){
      sum += z0[e]; sq += z0[e]*z0[e];
      sum += z1[e]; sq += z1[e]*z1[e];
      af[e]   = (short)f2bf(z0[e]);
      af[e+4] = (short)f2bf(z1[e]);
    }
    acc = __builtin_amdgcn_mfma_f32_16x16x32_bf16(af, bfrag[s], acc, 0, 0, 0);
  }
  sum += __shfl_xor(sum, 16); sum += __shfl_xor(sum, 32);
  sq  += __shfl_xor(sq , 16); sq  += __shfl_xor(sq , 32);
  float mean = sum * (1.f/CZ);
  float var  = sq  * (1.f/CZ) - mean*mean;
  float rstd = rsqrtf(var + 1e-5f);

  __shared__ float ob[NH][65];
  #pragma unroll
  for (int r = 0; r < 4; ++r){
    int row = q*4 + r;
    float mr = __shfl(mean, row);
    float rr = __shfl(rstd, row);
    ob[m][wave*16 + row] = rr * (acc[r] - mr * sumw) + sumb;
  }
  __syncthreads();
  size_t base = (size_t)i * N_SEQ + j0;
  #pragma unroll
  for (int rep = 0; rep < 4; ++rep){
    int idx = threadIdx.x + rep*256;
    int hh = idx >> 6;
    int jj = idx & 63;
    bias[(size_t)hh * ((size_t)N_SEQ*N_SEQ) + base + jj] = f2bf(ob[hh][jj]);
  }
}

// ---------------- K4: fused attention (no max-tracking: logits bounded) ----------------
#define TJ 128
#define KROW 20
__global__ __launch_bounds__(256) void attn_kernel(
    const float* __restrict__ qq, const float* __restrict__ kk,
    const float* __restrict__ vv, const float* __restrict__ gg,
    const unsigned short* __restrict__ bias, float* __restrict__ att)
{
  int h  = blockIdx.x & 15;
  int i0 = (blockIdx.x >> 4) * 16;
  int il = threadIdx.x & 15;
  int jg = threadIdx.x >> 4;

  __shared__ unsigned int smem[TJ*KROW*2];

  float qr[24];
  {
    const float* qs = qq + (size_t)(i0+il)*CS + h*CH;
    #pragma unroll
    for (int e = 0; e < 6; ++e){
      floatx4 t4 = *(const floatx4*)(qs + 4*e);
      qr[4*e] = t4[0]; qr[4*e+1] = t4[1]; qr[4*e+2] = t4[2]; qr[4*e+3] = t4[3];
    }
  }
  const float scale = 0.20412414523193154f; // 1/sqrt(24)
  float lrun = 0.f;
  float o[24];
  #pragma unroll
  for (int d = 0; d < 24; ++d) o[d] = 0.f;

  for (int jt = 0; jt < 8; ++jt){
    __syncthreads();
    {
      int row  = threadIdx.x >> 1;
      int half = threadIdx.x & 1;
      const float* ks = kk + (size_t)(jt*TJ + row)*CS + h*CH + half*12;
      const float* vs = vv + (size_t)(jt*TJ + row)*CS + h*CH + half*12;
      floatx4 ka = *(const floatx4*)(ks);
      floatx4 kb = *(const floatx4*)(ks+4);
      floatx4 kc = *(const floatx4*)(ks+8);
      floatx4 va = *(const floatx4*)(vs);
      floatx4 vb = *(const floatx4*)(vs+4);
      floatx4 vc = *(const floatx4*)(vs+8);
      unsigned int* kd = smem + row*KROW + half*6;
      unsigned int* vd = smem + TJ*KROW + row*KROW + half*6;
      uintx2 p0, p1, p2;
      p0[0] = (unsigned)f2bf(ka[0]) | ((unsigned)f2bf(ka[1])<<16);
      p0[1] = (unsigned)f2bf(ka[2]) | ((unsigned)f2bf(ka[3])<<16);
      p1[0] = (unsigned)f2bf(kb[0]) | ((unsigned)f2bf(kb[1])<<16);
      p1[1] = (unsigned)f2bf(kb[2]) | ((unsigned)f2bf(kb[3])<<16);
      p2[0] = (unsigned)f2bf(kc[0]) | ((unsigned)f2bf(kc[1])<<16);
      p2[1] = (unsigned)f2bf(kc[2]) | ((unsigned)f2bf(kc[3])<<16);
      *(uintx2*)(kd)   = p0;
      *(uintx2*)(kd+2) = p1;
      *(uintx2*)(kd+4) = p2;
      p0[0] = (unsigned)f2bf(va[0]) | ((unsigned)f2bf(va[1])<<16);
      p0[1] = (unsigned)f2bf(va[2]) | ((unsigned)f2bf(va[3])<<16);
      p1[0] = (unsigned)f2bf(vb[0]) | ((unsigned)f2bf(vb[1])<<16);
      p1[1] = (unsigned)f2bf(vb[2]) | ((unsigned)f2bf(vb[3])<<16);
      p2[0] = (unsigned)f2bf(vc[0]) | ((unsigned)f2bf(vc[1])<<16);
      p2[1] = (unsigned)f2bf(vc[2]) | ((unsigned)f2bf(vc[3])<<16);
      *(uintx2*)(vd)   = p0;
      *(uintx2*)(vd+2) = p1;
      *(uintx2*)(vd+4) = p2;
    }
    __syncthreads();
    const unsigned short* bptr = bias + (size_t)h*((size_t)N_SEQ*N_SEQ)
                               + (size_t)(i0+il)*N_SEQ + jt*TJ;
    #pragma unroll
    for (int tt = 0; tt < 8; ++tt){
      int jl = jg + 16*tt;
      uintx4 k0 = *(const uintx4*)&smem[jl*KROW];
      uintx4 k1 = *(const uintx4*)&smem[jl*KROW + 4];
      uintx4 k2 = *(const uintx4*)&smem[jl*KROW + 8];
      float dot = 0.f;
      #pragma unroll
      for (int e = 0; e < 4; ++e){
        dot += bf_lo(k0[e])*qr[2*e]      + bf_hi(k0[e])*qr[2*e+1];
        dot += bf_lo(k1[e])*qr[8+2*e]    + bf_hi(k1[e])*qr[8+2*e+1];
        dot += bf_lo(k2[e])*qr[16+2*e]   + bf_hi(k2[e])*qr[16+2*e+1];
      }
      float p = __expf(dot * scale + bf2f(bptr[jl]));
      lrun += p;
      uintx4 v0 = *(const uintx4*)&smem[TJ*KROW + jl*KROW];
      uintx4 v1 = *(const uintx4*)&smem[TJ*KROW + jl*KROW + 4];
      uintx4 v2 = *(const uintx4*)&smem[TJ*KROW + jl*KROW + 8];
      #pragma unroll
      for (int e = 0; e < 4; ++e){
        o[2*e]      += p * bf_lo(v0[e]);  o[2*e+1]    += p * bf_hi(v0[e]);
        o[8+2*e]    += p * bf_lo(v1[e]);  o[8+2*e+1]  += p * bf_hi(v1[e]);
        o[16+2*e]   += p * bf_lo(v2[e]);  o[16+2*e+1] += p * bf_hi(v2[e]);
      }
    }
  }
  __syncthreads();
  #pragma unroll
  for (int d = 0; d < 24; ++d){
    o[d] += __shfl_xor(o[d], 16);
    o[d] += __shfl_xor(o[d], 32);
  }
  lrun += __shfl_xor(lrun, 16);
  lrun += __shfl_xor(lrun, 32);
  float* mgf = (float*)smem;
  int lane = threadIdx.x & 63;
  int w    = threadIdx.x >> 6;
  if (lane < 16){
    float* slot = mgf + (w*16 + lane)*25;
    slot[0] = lrun;
    #pragma unroll
    for (int d = 0; d < 24; ++d) slot[1+d] = o[d];
  }
  __syncthreads();
  if (threadIdx.x < 16){
    int ii = threadIdx.x;
    float L = 0.f, O[24];
    #pragma unroll
    for (int d = 0; d < 24; ++d) O[d] = 0.f;
    for (int w2 = 0; w2 < 4; ++w2){
      const float* slot = mgf + (w2*16 + ii)*25;
      L += slot[0];
      #pragma unroll
      for (int d = 0; d < 24; ++d) O[d] += slot[1+d];
    }
    const float* gs = gg + (size_t)(i0+ii)*CS + h*CH;
    float* os = att + (size_t)(i0+ii)*CS + h*CH;
    float invL = 1.f / L;
    #pragma unroll
    for (int d = 0; d < 24; ++d) os[d] = O[d] * invL * gs[d];
  }
}

extern "C" void kernel_launch(void* const* d_in, const int* in_sizes, int n_in,
                              void* d_out, int out_size, void* d_ws, size_t ws_size,
                              hipStream_t stream) {
  const float* a_i     = (const float*)d_in[0];
  const float* s_i     = (const float*)d_in[1];
  const float* z_ij    = (const float*)d_in[2];
  const float* lns_w   = (const float*)d_in[3];
  const float* ada_ws  = (const float*)d_in[4];
  const float* ada_bs  = (const float*)d_in[5];
  const float* ada_wns = (const float*)d_in[6];
  const float* wq      = (const float*)d_in[7];
  const float* bq      = (const float*)d_in[8];
  const float* wk      = (const float*)d_in[9];
  const float* wv      = (const float*)d_in[10];
  const float* lnb_w   = (const float*)d_in[11];
  const float* lnb_b   = (const float*)d_in[12];
  const float* wb      = (const float*)d_in[13];
  const float* wg      = (const float*)d_in[14];
  const float* wo      = (const float*)d_in[15];
  const float* wsm     = (const float*)d_in[16];
  const float* bsv     = (const float*)d_in[17];

  const size_t RC = (size_t)N_SEQ * CS;
  float* wsf  = (float*)d_ws;
  float* a    = wsf;
  float* qv   = wsf + RC;
  float* kv   = wsf + 2*RC;
  float* vvp  = wsf + 3*RC;
  float* gv   = wsf + 4*RC;
  float* attb = wsf + 5*RC;
  unsigned short* biasw  = (unsigned short*)(wsf + 6*RC);      // 32 MB
  unsigned short* wprodT = biasw + (size_t)NH*N_SEQ*N_SEQ;     // 4 KB
  float* sums            = (float*)(wprodT + NH*CZ);           // 128 B

  prep_kernel<<<1, 256, 0, stream>>>(lnb_w, lnb_b, wb, wprodT, sums);
  bias_kernel<<<N_SEQ*16, 256, 0, stream>>>(z_ij, wprodT, sums, biasw);
  adaln_kernel<<<N_SEQ/4, 384, 0, stream>>>(a_i, s_i, lns_w, ada_ws, ada_bs, ada_wns, a);
  qkvg_kernel<<<N_SEQ/4, 384, 0, stream>>>(a, wq, bq, wk, wv, wg, qv, kv, vvp, gv);
  attn_kernel<<<N_SEQ, 256, 0, stream>>>(qv, kv, vvp, gv, biasw, attb);
  final_kernel<<<N_SEQ/4, 384, 0, stream>>>(attb, wo, s_i, wsm, bsv, (float*)d_out);
}